// Round 10
// baseline (259.885 us; speedup 1.0000x reference)
//
#include <hip/hip_runtime.h>
#include <hip/hip_bf16.h>
#include <math.h>

#define T_N 32768
#define D_N 256
#define HID 32
#define LOG2E 1.44269504f
#define LN2   0.69314718f

typedef short  s16x8  __attribute__((ext_vector_type(8)));   // MFMA A/B frag
typedef float  f32x16 __attribute__((ext_vector_type(16)));  // MFMA C/D frag
typedef float  f32x4  __attribute__((ext_vector_type(4)));
typedef float  f32x2  __attribute__((ext_vector_type(2)));   // v_pk_*_f32 carrier

union FragU { s16x8 v; unsigned u[4]; unsigned short s[8]; };

// ---- conversions ----
// setup-path (once per block): full RNE via HIP API, proven rounds 4-9
static __device__ __forceinline__ unsigned short w2b(float f) {
    union { __hip_bfloat16 h; unsigned short s; } u;
    u.h = __float2bfloat16(f); return u.s;
}
// hot-path pack: round-half-up f32->bf16 pair, 3 full-rate VALU ops (r7-proven)
static __device__ __forceinline__ unsigned pkrh(float a, float b) {
    const unsigned ua = __float_as_uint(a) + 0x8000u;
    const unsigned ub = __float_as_uint(b) + 0x8000u;
#if __has_builtin(__builtin_amdgcn_perm)
    return __builtin_amdgcn_perm(ub, ua, 0x07060302u);  // {a.hi16 | b.hi16<<16}
#else
    return (ua >> 16) | (ub & 0xFFFF0000u);
#endif
}
static __device__ __forceinline__ unsigned pk2(f32x2 v) { return pkrh(v[0], v[1]); }
static __device__ __forceinline__ float exp2neg(float t) {   // 2^(-t)
#if __has_builtin(__builtin_amdgcn_exp2f)
    return __builtin_amdgcn_exp2f(-t);
#else
    return __expf(-t * LN2);
#endif
}

// quad scaled-silu with ONE rcp (Montgomery batched reciprocal):
//   d_i = 1 + 2^-t_i ; r = rcp(d0 d1 d2 d3); 1/d_i = r * prod(d_j, j!=i)
// 4 exp2 + 1 rcp (trans) + ~9 full-rate muls, vs 4 exp2 + 4 rcp before.
// Overflow safety: product > f32 max needs sum(preact) < -88 per quad
// (~30 sigma for this net); in that regime true silu == 0 and the r=0
// path returns 0 anyway. Extra rounding ~2 ulp -> invisible under bf16.
static __device__ __forceinline__ void act4(float t0, float t1, float t2, float t3,
                                            f32x2& oA, f32x2& oB) {
    f32x2 eA, eB;
    eA[0] = exp2neg(t0); eA[1] = exp2neg(t1);
    eB[0] = exp2neg(t2); eB[1] = exp2neg(t3);
    const f32x2 dA = eA + 1.0f;                  // v_pk_add_f32
    const f32x2 dB = eB + 1.0f;
    const float s0 = dA[0] * dA[1];
    const float s1 = dB[0] * dB[1];
    const float r  = __builtin_amdgcn_rcpf(s0 * s1);
    const float rA = r * s1, rB = r * s0;
    f32x2 iA; iA[0] = rA * dA[1]; iA[1] = rA * dA[0];
    f32x2 iB; iB[0] = rB * dB[1]; iB[1] = rB * dB[0];
    f32x2 tA; tA[0] = t0; tA[1] = t1;
    f32x2 tB; tB[0] = t2; tB[1] = t3;
    oA = tA * iA;                                 // v_pk_mul_f32
    oB = tB * iB;
}

// One observation t per wave; 8 chunks of 32 doses via 32x32x16 bf16 MFMA.
// Transposed form: D[m=unit][n=dose] = W^T(A) * h^T(B) + bias(C).
// Layouts (m74/m101, validated rounds 4-9):
//   A[m=lane&31][k=(lane>>5)*8+j], B[k=(lane>>5)*8+j][n=lane&31],
//   C/D: col=lane&31, row=(reg&3)+8*(reg>>2)+4*(lane>>5)
// exp2-domain scaling: W1,b1..b3 *log2e, W4 *ln2 (scales telescope).
// Feature k-order (dt, dt_last, amt, ss, ii): static features prepacked.
__global__ __launch_bounds__(256, 3) void dose_encoder_kernel(
    const float* __restrict__ t_abs,
    const float* __restrict__ dose_t,
    const float* __restrict__ amts,
    const float* __restrict__ ss,
    const float* __restrict__ ii,
    const float* __restrict__ span_p,
    const float* __restrict__ logsig_p,
    const float* __restrict__ W1, const float* __restrict__ b1,
    const float* __restrict__ W2, const float* __restrict__ b2,
    const float* __restrict__ W3, const float* __restrict__ b3,
    const float* __restrict__ W4, const float* __restrict__ b4,
    float* __restrict__ out)
{
    // pd: {dose_f32, bits(pk(amt,ss)), bits(pk(ii,0)), unused}
    __shared__ f32x4 pd[D_N];
    // per-wave transpose tile: [col n][row k], col stride 36 shorts = 72 B
    // (measured 0 bank conflicts rounds 5-9)
    __shared__ __align__(16) unsigned short tile[4][32][36];

    const int tid  = threadIdx.x;
    const int wv   = tid >> 6;
    const int lane = tid & 63;
    const int n    = lane & 31;       // dose column
    const int hh   = lane >> 5;       // k-half
    const int t    = blockIdx.x * 4 + wv;

    const float span   = span_p[0];
    const float inv_se = 1.0f / (span + 1e-6f);
    const float inv_sp = 1.0f / span;
    const float sigma  = __expf(logsig_p[0]);
    const float gk     = sqrtf(0.5f * LOG2E) / sigma;   // wgt = 2^(-(dt*gk)^2)

    { f32x4 e;
      e[0] = dose_t[tid];
      e[1] = __uint_as_float(((unsigned)w2b(log1pf(amts[tid]))) |
                             ((unsigned)w2b(ss[tid] * inv_se) << 16));
      e[2] = __uint_as_float((unsigned)w2b(ii[tid] * inv_se));
      e[3] = 0.0f;
      pd[tid] = e; }
    __syncthreads();

    const float tv  = t_abs[t];
    const float dtl = (tv - dose_t[D_N - 1]) * inv_sp;  // doses sorted, all < t_abs

    // ---- one-time weight fragments (wave-uniform addresses -> s_loads) ----
    // k-row order for layer 1: {dt, dt_last, amt, ss, ii} = W1 rows {0,2,1,3,4}
    FragU a1;
    {
        const int kmap[5] = {0, 2, 1, 3, 4};
        #pragma unroll
        for (int j = 0; j < 8; ++j) {
            const int k = hh * 8 + j;
            a1.s[j] = (k < 5) ? w2b(LOG2E * W1[kmap[k] * HID + n]) : (unsigned short)0;
        }
    }
    FragU a2[2], a3[2];
    #pragma unroll
    for (int mf = 0; mf < 2; ++mf)
        #pragma unroll
        for (int j = 0; j < 8; ++j) {
            const int k = mf * 16 + hh * 8 + j;
            a2[mf].s[j] = w2b(W2[k * HID + n]);
            a3[mf].s[j] = w2b(W3[k * HID + n]);
        }
    f32x16 c1, c2, c3; f32x2 w4p[8];
    #pragma unroll
    for (int r = 0; r < 16; ++r) {
        const int row = (r & 3) + 8 * (r >> 2) + 4 * hh;
        c1[r] = LOG2E * b1[row];
        c2[r] = LOG2E * b2[row];
        c3[r] = LOG2E * b3[row];
        w4p[r >> 1][r & 1] = LN2 * W4[row];
    }
    const float b4s = b4[0];

    unsigned short (* const tl)[36] = tile[wv];

    float acc = 0.0f;
    #pragma unroll 2
    for (int c = 0; c < 8; ++c) {
        const f32x4 p   = pd[c * 32 + n];
        const float dtv = (tv - p[0]) * inv_sp;

        // feature B-frag: rows k=0..4 live in hh=0 lanes; A rows k>=5 are zero,
        // so hh=1 lanes' contents are annihilated -> no masking needed.
        FragU bf;
        bf.u[0] = pkrh(dtv, dtl);            // k0=dt, k1=dt_last (1 dynamic pack)
        bf.u[1] = __float_as_uint(p[1]);     // k2=amt, k3=ss (prepacked)
        bf.u[2] = __float_as_uint(p[2]);     // k4=ii, k5=0   (prepacked)
        bf.u[3] = 0u;

        // ---- layer 1 (K=16 covers 5 features) ----
        f32x16 h = __builtin_amdgcn_mfma_f32_32x32x16_bf16(a1.v, bf.v, c1, 0, 0, 0);

        #pragma unroll
        for (int G = 0; G < 4; ++G) {   // rows 8G+4hh+{0..3} of col n
            f32x2 oA, oB;
            act4(h[4*G], h[4*G+1], h[4*G+2], h[4*G+3], oA, oB);
            uint2 wd; wd.x = pk2(oA); wd.y = pk2(oB);
            *(uint2*)&tl[n][8*G + 4*hh] = wd;
        }
        FragU bh0, bh1;
        { const uint2 r0 = *(const uint2*)&tl[n][8*hh];
          const uint2 r1 = *(const uint2*)&tl[n][8*hh + 4];
          const uint2 r2 = *(const uint2*)&tl[n][16 + 8*hh];
          const uint2 r3 = *(const uint2*)&tl[n][16 + 8*hh + 4];
          bh0.u[0] = r0.x; bh0.u[1] = r0.y; bh0.u[2] = r1.x; bh0.u[3] = r1.y;
          bh1.u[0] = r2.x; bh1.u[1] = r2.y; bh1.u[2] = r3.x; bh1.u[3] = r3.y; }

        // ---- layer 2 (K=32 as two chained K=16) ----
        h = __builtin_amdgcn_mfma_f32_32x32x16_bf16(a2[0].v, bh0.v, c2, 0, 0, 0);
        h = __builtin_amdgcn_mfma_f32_32x32x16_bf16(a2[1].v, bh1.v, h,  0, 0, 0);

        #pragma unroll
        for (int G = 0; G < 4; ++G) {
            f32x2 oA, oB;
            act4(h[4*G], h[4*G+1], h[4*G+2], h[4*G+3], oA, oB);
            uint2 wd; wd.x = pk2(oA); wd.y = pk2(oB);
            *(uint2*)&tl[n][8*G + 4*hh] = wd;
        }
        { const uint2 r0 = *(const uint2*)&tl[n][8*hh];
          const uint2 r1 = *(const uint2*)&tl[n][8*hh + 4];
          const uint2 r2 = *(const uint2*)&tl[n][16 + 8*hh];
          const uint2 r3 = *(const uint2*)&tl[n][16 + 8*hh + 4];
          bh0.u[0] = r0.x; bh0.u[1] = r0.y; bh0.u[2] = r1.x; bh0.u[3] = r1.y;
          bh1.u[0] = r2.x; bh1.u[1] = r2.y; bh1.u[2] = r3.x; bh1.u[3] = r3.y; }

        // ---- layer 3 + head (packed fma accumulation) ----
        h = __builtin_amdgcn_mfma_f32_32x32x16_bf16(a3[0].v, bh0.v, c3, 0, 0, 0);
        h = __builtin_amdgcn_mfma_f32_32x32x16_bf16(a3[1].v, bh1.v, h,  0, 0, 0);

        f32x2 pacc = {0.0f, 0.0f};
        #pragma unroll
        for (int r = 0; r < 16; r += 4) {
            f32x2 oA, oB;
            act4(h[r], h[r+1], h[r+2], h[r+3], oA, oB);
            pacc += oA * w4p[r >> 1];            // v_pk_fma_f32
            pacc += oB * w4p[(r >> 1) + 1];
        }
        float part = pacc[0] + pacc[1];
        part += __shfl_xor(part, 32, 64);       // sum the two k-halves
        const float score = part + b4s;

        const float q   = dtv * gk;
        float wgt = exp2neg(q * q);
        wgt = (dtv >= 0.0f) ? wgt : 0.0f;
        acc = fmaf(score, wgt, acc);
    }

    // reduce over the 32 dose-columns (halves are duplicates)
    #pragma unroll
    for (int off = 1; off < 32; off <<= 1)
        acc += __shfl_xor(acc, off, 64);
    if (lane == 0) out[t] = acc;
}

extern "C" void kernel_launch(void* const* d_in, const int* in_sizes, int n_in,
                              void* d_out, int out_size, void* d_ws, size_t ws_size,
                              hipStream_t stream) {
    const float* t_abs  = (const float*)d_in[0];
    const float* dose_t = (const float*)d_in[1];
    const float* amts   = (const float*)d_in[2];
    const float* ss     = (const float*)d_in[3];
    const float* ii     = (const float*)d_in[4];
    const float* span_p = (const float*)d_in[5];
    const float* logsig = (const float*)d_in[6];
    const float* W1 = (const float*)d_in[7];
    const float* b1 = (const float*)d_in[8];
    const float* W2 = (const float*)d_in[9];
    const float* b2 = (const float*)d_in[10];
    const float* W3 = (const float*)d_in[11];
    const float* b3 = (const float*)d_in[12];
    const float* W4 = (const float*)d_in[13];
    const float* b4 = (const float*)d_in[14];
    float* out = (float*)d_out;

    dose_encoder_kernel<<<dim3(T_N / 4), dim3(256), 0, stream>>>(
        t_abs, dose_t, amts, ss, ii, span_p, logsig,
        W1, b1, W2, b2, W3, b3, W4, b4, out);
}

// Round 11
// 257.348 us; speedup vs baseline: 1.0099x; 1.0099x over previous
//
#include <hip/hip_runtime.h>
#include <hip/hip_bf16.h>
#include <math.h>

#define T_N 32768
#define D_N 256
#define HID 32
#define LOG2E 1.44269504f
#define LN2   0.69314718f

typedef short  s16x8  __attribute__((ext_vector_type(8)));   // MFMA A/B frag
typedef float  f32x16 __attribute__((ext_vector_type(16)));  // MFMA C/D frag
typedef float  f32x4  __attribute__((ext_vector_type(4)));
typedef float  f32x2  __attribute__((ext_vector_type(2)));   // v_pk_*_f32 carrier

union FragU { s16x8 v; unsigned u[4]; unsigned short s[8]; };

// ---- conversions ----
// setup-path (once per block): full RNE via HIP API, proven rounds 4-10
static __device__ __forceinline__ unsigned short w2b(float f) {
    union { __hip_bfloat16 h; unsigned short s; } u;
    u.h = __float2bfloat16(f); return u.s;
}
// hot-path pack: round-half-up f32->bf16 pair, 3 full-rate VALU ops (r7-proven)
static __device__ __forceinline__ unsigned pkrh(float a, float b) {
    const unsigned ua = __float_as_uint(a) + 0x8000u;
    const unsigned ub = __float_as_uint(b) + 0x8000u;
#if __has_builtin(__builtin_amdgcn_perm)
    return __builtin_amdgcn_perm(ub, ua, 0x07060302u);  // {a.hi16 | b.hi16<<16}
#else
    return (ua >> 16) | (ub & 0xFFFF0000u);
#endif
}
static __device__ __forceinline__ unsigned pk2(f32x2 v) { return pkrh(v[0], v[1]); }
static __device__ __forceinline__ float exp2neg(float t) {   // 2^(-t)
#if __has_builtin(__builtin_amdgcn_exp2f)
    return __builtin_amdgcn_exp2f(-t);
#else
    return __expf(-t * LN2);
#endif
}
// paired scaled-silu (r9 shape — r10's batched-rcp variant REGRESSED 195->215:
// short chains beat fewer trans ops on this pipe; keep 2 exp2 + 2 rcp).
static __device__ __forceinline__ f32x2 act2(float a, float b) {
    f32x2 e; e[0] = exp2neg(a); e[1] = exp2neg(b);
    const f32x2 d = e + 1.0f;                       // v_pk_add_f32
    f32x2 r; r[0] = __builtin_amdgcn_rcpf(d[0]); r[1] = __builtin_amdgcn_rcpf(d[1]);
    f32x2 t; t[0] = a; t[1] = b;
    return t * r;                                    // v_pk_mul_f32
}

// One observation t per wave; 8 chunks of 32 doses via 32x32x16 bf16 MFMA.
// Transposed form: D[m=unit][n=dose] = W^T(A) * h^T(B) + bias(C).
// Layouts (m74/m101, validated rounds 4-10):
//   A[m=lane&31][k=(lane>>5)*8+j], B[k=(lane>>5)*8+j][n=lane&31],
//   C/D: col=lane&31, row=(reg&3)+8*(reg>>2)+4*(lane>>5)
// exp2-domain scaling: W1,b1..b3 *log2e, W4 *ln2 (scales telescope).
//
// Layer transition WITHOUT LDS (new in r11): the C->B relayout only crosses
// the two 32-lane halves. Packing reg pairs gives P0..P7 with
//   P0=rows 4hh+{0,1}, P1=4hh+{2,3}, P2=8+4hh+{0,1}, P3=8+4hh+{2,3},
//   P4=16+4hh+{0,1},P5=16+4hh+{2,3},P6=24+4hh+{0,1},P7=24+4hh+{2,3}
// B-frag bh0 (k=0..15) / bh1 (k=16..31) then assemble from own {P} and
// partner (lane^32) values: send V0..V3 = hh?{P0,P1,P4,P5}:{P2,P3,P6,P7}
// via __shfl_xor(32) and cndmask into place. 4 shfl + 12 sel replace
// 8 LDS ops + addressing + lgkmcnt waits per transition.
__global__ __launch_bounds__(256, 3) void dose_encoder_kernel(
    const float* __restrict__ t_abs,
    const float* __restrict__ dose_t,
    const float* __restrict__ amts,
    const float* __restrict__ ss,
    const float* __restrict__ ii,
    const float* __restrict__ span_p,
    const float* __restrict__ logsig_p,
    const float* __restrict__ W1, const float* __restrict__ b1,
    const float* __restrict__ W2, const float* __restrict__ b2,
    const float* __restrict__ W3, const float* __restrict__ b3,
    const float* __restrict__ W4, const float* __restrict__ b4,
    float* __restrict__ out)
{
    // pd: {dose_f32, bits(pk(amt,ss)), bits(pk(ii,0)), unused}
    __shared__ f32x4 pd[D_N];

    const int tid  = threadIdx.x;
    const int wv   = tid >> 6;
    const int lane = tid & 63;
    const int n    = lane & 31;       // dose column
    const int hh   = lane >> 5;       // k-half
    const bool hi  = (hh != 0);
    const int t    = blockIdx.x * 4 + wv;

    const float span   = span_p[0];
    const float inv_se = 1.0f / (span + 1e-6f);
    const float inv_sp = 1.0f / span;
    const float sigma  = __expf(logsig_p[0]);
    const float gk     = sqrtf(0.5f * LOG2E) / sigma;   // wgt = 2^(-(dt*gk)^2)

    { f32x4 e;
      e[0] = dose_t[tid];
      e[1] = __uint_as_float(((unsigned)w2b(log1pf(amts[tid]))) |
                             ((unsigned)w2b(ss[tid] * inv_se) << 16));
      e[2] = __uint_as_float((unsigned)w2b(ii[tid] * inv_se));
      e[3] = 0.0f;
      pd[tid] = e; }
    __syncthreads();

    const float tv  = t_abs[t];
    const float dtl = (tv - dose_t[D_N - 1]) * inv_sp;  // doses sorted, all < t_abs

    // ---- one-time weight fragments (wave-uniform addresses -> s_loads) ----
    // k-row order for layer 1: {dt, dt_last, amt, ss, ii} = W1 rows {0,2,1,3,4}
    FragU a1;
    {
        const int kmap[5] = {0, 2, 1, 3, 4};
        #pragma unroll
        for (int j = 0; j < 8; ++j) {
            const int k = hh * 8 + j;
            a1.s[j] = (k < 5) ? w2b(LOG2E * W1[kmap[k] * HID + n]) : (unsigned short)0;
        }
    }
    FragU a2[2], a3[2];
    #pragma unroll
    for (int mf = 0; mf < 2; ++mf)
        #pragma unroll
        for (int j = 0; j < 8; ++j) {
            const int k = mf * 16 + hh * 8 + j;
            a2[mf].s[j] = w2b(W2[k * HID + n]);
            a3[mf].s[j] = w2b(W3[k * HID + n]);
        }
    f32x16 c1, c2, c3; f32x2 w4p[8];
    #pragma unroll
    for (int r = 0; r < 16; ++r) {
        const int row = (r & 3) + 8 * (r >> 2) + 4 * hh;
        c1[r] = LOG2E * b1[row];
        c2[r] = LOG2E * b2[row];
        c3[r] = LOG2E * b3[row];
        w4p[r >> 1][r & 1] = LN2 * W4[row];
    }
    const float b4s = b4[0];

    float acc = 0.0f;
    #pragma unroll 2
    for (int c = 0; c < 8; ++c) {
        const f32x4 p   = pd[c * 32 + n];
        const float dtv = (tv - p[0]) * inv_sp;

        // feature B-frag: rows k=0..4 live in hh=0 lanes; A rows k>=5 are zero,
        // so hh=1 lanes' contents are annihilated -> no masking needed.
        FragU bf;
        bf.u[0] = pkrh(dtv, dtl);            // k0=dt, k1=dt_last (1 dynamic pack)
        bf.u[1] = __float_as_uint(p[1]);     // k2=amt, k3=ss (prepacked)
        bf.u[2] = __float_as_uint(p[2]);     // k4=ii, k5=0   (prepacked)
        bf.u[3] = 0u;

        // ---- layer 1 (K=16 covers 5 features) ----
        f32x16 h = __builtin_amdgcn_mfma_f32_32x32x16_bf16(a1.v, bf.v, c1, 0, 0, 0);

        FragU bh0, bh1;
        {
            unsigned P[8];
            #pragma unroll
            for (int i = 0; i < 8; ++i) P[i] = pk2(act2(h[2*i], h[2*i+1]));
            const unsigned X0 = (unsigned)__shfl_xor((int)(hi ? P[0] : P[2]), 32, 64);
            const unsigned X1 = (unsigned)__shfl_xor((int)(hi ? P[1] : P[3]), 32, 64);
            const unsigned X2 = (unsigned)__shfl_xor((int)(hi ? P[4] : P[6]), 32, 64);
            const unsigned X3 = (unsigned)__shfl_xor((int)(hi ? P[5] : P[7]), 32, 64);
            bh0.u[0] = hi ? X0 : P[0];  bh0.u[1] = hi ? X1 : P[1];
            bh0.u[2] = hi ? P[2] : X0;  bh0.u[3] = hi ? P[3] : X1;
            bh1.u[0] = hi ? X2 : P[4];  bh1.u[1] = hi ? X3 : P[5];
            bh1.u[2] = hi ? P[6] : X2;  bh1.u[3] = hi ? P[7] : X3;
        }

        // ---- layer 2 (K=32 as two chained K=16) ----
        h = __builtin_amdgcn_mfma_f32_32x32x16_bf16(a2[0].v, bh0.v, c2, 0, 0, 0);
        h = __builtin_amdgcn_mfma_f32_32x32x16_bf16(a2[1].v, bh1.v, h,  0, 0, 0);

        {
            unsigned P[8];
            #pragma unroll
            for (int i = 0; i < 8; ++i) P[i] = pk2(act2(h[2*i], h[2*i+1]));
            const unsigned X0 = (unsigned)__shfl_xor((int)(hi ? P[0] : P[2]), 32, 64);
            const unsigned X1 = (unsigned)__shfl_xor((int)(hi ? P[1] : P[3]), 32, 64);
            const unsigned X2 = (unsigned)__shfl_xor((int)(hi ? P[4] : P[6]), 32, 64);
            const unsigned X3 = (unsigned)__shfl_xor((int)(hi ? P[5] : P[7]), 32, 64);
            bh0.u[0] = hi ? X0 : P[0];  bh0.u[1] = hi ? X1 : P[1];
            bh0.u[2] = hi ? P[2] : X0;  bh0.u[3] = hi ? P[3] : X1;
            bh1.u[0] = hi ? X2 : P[4];  bh1.u[1] = hi ? X3 : P[5];
            bh1.u[2] = hi ? P[6] : X2;  bh1.u[3] = hi ? P[7] : X3;
        }

        // ---- layer 3 + head (packed fma accumulation) ----
        h = __builtin_amdgcn_mfma_f32_32x32x16_bf16(a3[0].v, bh0.v, c3, 0, 0, 0);
        h = __builtin_amdgcn_mfma_f32_32x32x16_bf16(a3[1].v, bh1.v, h,  0, 0, 0);

        f32x2 pacc = {0.0f, 0.0f};
        #pragma unroll
        for (int r = 0; r < 16; r += 2)
            pacc += act2(h[r], h[r+1]) * w4p[r >> 1];   // v_pk_fma_f32
        float part = pacc[0] + pacc[1];
        part += __shfl_xor(part, 32, 64);       // sum the two k-halves
        const float score = part + b4s;

        const float q   = dtv * gk;
        float wgt = exp2neg(q * q);
        wgt = (dtv >= 0.0f) ? wgt : 0.0f;
        acc = fmaf(score, wgt, acc);
    }

    // reduce over the 32 dose-columns (halves are duplicates)
    #pragma unroll
    for (int off = 1; off < 32; off <<= 1)
        acc += __shfl_xor(acc, off, 64);
    if (lane == 0) out[t] = acc;
}

extern "C" void kernel_launch(void* const* d_in, const int* in_sizes, int n_in,
                              void* d_out, int out_size, void* d_ws, size_t ws_size,
                              hipStream_t stream) {
    const float* t_abs  = (const float*)d_in[0];
    const float* dose_t = (const float*)d_in[1];
    const float* amts   = (const float*)d_in[2];
    const float* ss     = (const float*)d_in[3];
    const float* ii     = (const float*)d_in[4];
    const float* span_p = (const float*)d_in[5];
    const float* logsig = (const float*)d_in[6];
    const float* W1 = (const float*)d_in[7];
    const float* b1 = (const float*)d_in[8];
    const float* W2 = (const float*)d_in[9];
    const float* b2 = (const float*)d_in[10];
    const float* W3 = (const float*)d_in[11];
    const float* b3 = (const float*)d_in[12];
    const float* W4 = (const float*)d_in[13];
    const float* b4 = (const float*)d_in[14];
    float* out = (float*)d_out;

    dose_encoder_kernel<<<dim3(T_N / 4), dim3(256), 0, stream>>>(
        t_abs, dose_t, amts, ss, ii, span_p, logsig,
        W1, b1, W2, b2, W3, b3, W4, b4, out);
}

// Round 12
// 248.727 us; speedup vs baseline: 1.0449x; 1.0347x over previous
//
#include <hip/hip_runtime.h>
#include <hip/hip_bf16.h>
#include <math.h>

#define T_N 32768
#define D_N 256
#define HID 32
#define LOG2E 1.44269504f
#define LN2   0.69314718f

typedef short  s16x8  __attribute__((ext_vector_type(8)));   // MFMA A/B frag
typedef float  f32x16 __attribute__((ext_vector_type(16)));  // MFMA C/D frag
typedef float  f32x4  __attribute__((ext_vector_type(4)));
typedef float  f32x2  __attribute__((ext_vector_type(2)));   // v_pk_*_f32 carrier

union FragU { s16x8 v; unsigned u[4]; unsigned short s[8]; };

// ---- conversions ----
// setup-path (once per block): full RNE via HIP API, proven rounds 4-11
static __device__ __forceinline__ unsigned short w2b(float f) {
    union { __hip_bfloat16 h; unsigned short s; } u;
    u.h = __float2bfloat16(f); return u.s;
}
// hot-path pack: round-half-up f32->bf16 pair, 3 full-rate VALU ops (r7-proven)
static __device__ __forceinline__ unsigned pkrh(float a, float b) {
    const unsigned ua = __float_as_uint(a) + 0x8000u;
    const unsigned ub = __float_as_uint(b) + 0x8000u;
#if __has_builtin(__builtin_amdgcn_perm)
    return __builtin_amdgcn_perm(ub, ua, 0x07060302u);  // {a.hi16 | b.hi16<<16}
#else
    return (ua >> 16) | (ub & 0xFFFF0000u);
#endif
}
static __device__ __forceinline__ unsigned pk2(f32x2 v) { return pkrh(v[0], v[1]); }
static __device__ __forceinline__ float exp2neg(float t) {   // 2^(-t)
#if __has_builtin(__builtin_amdgcn_exp2f)
    return __builtin_amdgcn_exp2f(-t);
#else
    return __expf(-t * LN2);
#endif
}
// paired scaled-silu (r9 shape). r10's batched-rcp REGRESSED (195->215):
// short chains beat fewer trans ops. Keep 2 exp2 + 2 rcp, pk add/mul.
static __device__ __forceinline__ f32x2 act2(float a, float b) {
    f32x2 e; e[0] = exp2neg(a); e[1] = exp2neg(b);
    const f32x2 d = e + 1.0f;                       // v_pk_add_f32
    f32x2 r; r[0] = __builtin_amdgcn_rcpf(d[0]); r[1] = __builtin_amdgcn_rcpf(d[1]);
    f32x2 t; t[0] = a; t[1] = b;
    return t * r;                                    // v_pk_mul_f32
}

// One observation t per wave; 8 chunks of 32 doses via 32x32x16 bf16 MFMA.
// Transposed form: D[m=unit][n=dose] = W^T(A) * h^T(B) + bias(C).
// Layouts (m74/m101, validated rounds 4-11):
//   A[m=lane&31][k=(lane>>5)*8+j], B[k=(lane>>5)*8+j][n=lane&31],
//   C/D: col=lane&31, row=(reg&3)+8*(reg>>2)+4*(lane>>5)
// exp2-domain scaling: W1,b1..b3 *log2e, W4 *ln2 (scales telescope).
// Layer transition via per-wave LDS tile (72B col stride, 0 conflicts
// measured r5-r9). r11's shfl_xor+cndmask variant REGRESSED (195->206):
// ds_bpermute is the same LDS pipe plus extra VALU selects.
// Chunk loop unroll 4 (r12 experiment): expose cross-chunk independent
// chains to cover the 15% VALU-idle latency gap seen at unroll 2.
__global__ __launch_bounds__(256, 3) void dose_encoder_kernel(
    const float* __restrict__ t_abs,
    const float* __restrict__ dose_t,
    const float* __restrict__ amts,
    const float* __restrict__ ss,
    const float* __restrict__ ii,
    const float* __restrict__ span_p,
    const float* __restrict__ logsig_p,
    const float* __restrict__ W1, const float* __restrict__ b1,
    const float* __restrict__ W2, const float* __restrict__ b2,
    const float* __restrict__ W3, const float* __restrict__ b3,
    const float* __restrict__ W4, const float* __restrict__ b4,
    float* __restrict__ out)
{
    // pd: {dose_f32, bits(pk(amt,ss)), bits(pk(ii,0)), unused}
    __shared__ f32x4 pd[D_N];
    // per-wave transpose tile: [col n][row k], col stride 36 shorts = 72 B
    __shared__ __align__(16) unsigned short tile[4][32][36];

    const int tid  = threadIdx.x;
    const int wv   = tid >> 6;
    const int lane = tid & 63;
    const int n    = lane & 31;       // dose column
    const int hh   = lane >> 5;       // k-half
    const int t    = blockIdx.x * 4 + wv;

    const float span   = span_p[0];
    const float inv_se = 1.0f / (span + 1e-6f);
    const float inv_sp = 1.0f / span;
    const float sigma  = __expf(logsig_p[0]);
    const float gk     = sqrtf(0.5f * LOG2E) / sigma;   // wgt = 2^(-(dt*gk)^2)

    { f32x4 e;
      e[0] = dose_t[tid];
      e[1] = __uint_as_float(((unsigned)w2b(log1pf(amts[tid]))) |
                             ((unsigned)w2b(ss[tid] * inv_se) << 16));
      e[2] = __uint_as_float((unsigned)w2b(ii[tid] * inv_se));
      e[3] = 0.0f;
      pd[tid] = e; }
    __syncthreads();

    const float tv  = t_abs[t];
    const float dtl = (tv - dose_t[D_N - 1]) * inv_sp;  // doses sorted, all < t_abs

    // ---- one-time weight fragments (wave-uniform addresses -> s_loads) ----
    // k-row order for layer 1: {dt, dt_last, amt, ss, ii} = W1 rows {0,2,1,3,4}
    FragU a1;
    {
        const int kmap[5] = {0, 2, 1, 3, 4};
        #pragma unroll
        for (int j = 0; j < 8; ++j) {
            const int k = hh * 8 + j;
            a1.s[j] = (k < 5) ? w2b(LOG2E * W1[kmap[k] * HID + n]) : (unsigned short)0;
        }
    }
    FragU a2[2], a3[2];
    #pragma unroll
    for (int mf = 0; mf < 2; ++mf)
        #pragma unroll
        for (int j = 0; j < 8; ++j) {
            const int k = mf * 16 + hh * 8 + j;
            a2[mf].s[j] = w2b(W2[k * HID + n]);
            a3[mf].s[j] = w2b(W3[k * HID + n]);
        }
    f32x16 c1, c2, c3; f32x2 w4p[8];
    #pragma unroll
    for (int r = 0; r < 16; ++r) {
        const int row = (r & 3) + 8 * (r >> 2) + 4 * hh;
        c1[r] = LOG2E * b1[row];
        c2[r] = LOG2E * b2[row];
        c3[r] = LOG2E * b3[row];
        w4p[r >> 1][r & 1] = LN2 * W4[row];
    }
    const float b4s = b4[0];

    unsigned short (* const tl)[36] = tile[wv];

    float acc = 0.0f;
    #pragma unroll 4
    for (int c = 0; c < 8; ++c) {
        const f32x4 p   = pd[c * 32 + n];
        const float dtv = (tv - p[0]) * inv_sp;

        // feature B-frag: rows k=0..4 live in hh=0 lanes; A rows k>=5 are zero,
        // so hh=1 lanes' contents are annihilated -> no masking needed.
        FragU bf;
        bf.u[0] = pkrh(dtv, dtl);            // k0=dt, k1=dt_last (1 dynamic pack)
        bf.u[1] = __float_as_uint(p[1]);     // k2=amt, k3=ss (prepacked)
        bf.u[2] = __float_as_uint(p[2]);     // k4=ii, k5=0   (prepacked)
        bf.u[3] = 0u;

        // ---- layer 1 (K=16 covers 5 features) ----
        f32x16 h = __builtin_amdgcn_mfma_f32_32x32x16_bf16(a1.v, bf.v, c1, 0, 0, 0);

        #pragma unroll
        for (int G = 0; G < 4; ++G) {   // rows 8G+4hh+{0..3} of col n
            uint2 wd;
            wd.x = pk2(act2(h[4*G],   h[4*G+1]));
            wd.y = pk2(act2(h[4*G+2], h[4*G+3]));
            *(uint2*)&tl[n][8*G + 4*hh] = wd;
        }
        FragU bh0, bh1;
        { const uint2 r0 = *(const uint2*)&tl[n][8*hh];
          const uint2 r1 = *(const uint2*)&tl[n][8*hh + 4];
          const uint2 r2 = *(const uint2*)&tl[n][16 + 8*hh];
          const uint2 r3 = *(const uint2*)&tl[n][16 + 8*hh + 4];
          bh0.u[0] = r0.x; bh0.u[1] = r0.y; bh0.u[2] = r1.x; bh0.u[3] = r1.y;
          bh1.u[0] = r2.x; bh1.u[1] = r2.y; bh1.u[2] = r3.x; bh1.u[3] = r3.y; }

        // ---- layer 2 (K=32 as two chained K=16) ----
        h = __builtin_amdgcn_mfma_f32_32x32x16_bf16(a2[0].v, bh0.v, c2, 0, 0, 0);
        h = __builtin_amdgcn_mfma_f32_32x32x16_bf16(a2[1].v, bh1.v, h,  0, 0, 0);

        #pragma unroll
        for (int G = 0; G < 4; ++G) {
            uint2 wd;
            wd.x = pk2(act2(h[4*G],   h[4*G+1]));
            wd.y = pk2(act2(h[4*G+2], h[4*G+3]));
            *(uint2*)&tl[n][8*G + 4*hh] = wd;
        }
        { const uint2 r0 = *(const uint2*)&tl[n][8*hh];
          const uint2 r1 = *(const uint2*)&tl[n][8*hh + 4];
          const uint2 r2 = *(const uint2*)&tl[n][16 + 8*hh];
          const uint2 r3 = *(const uint2*)&tl[n][16 + 8*hh + 4];
          bh0.u[0] = r0.x; bh0.u[1] = r0.y; bh0.u[2] = r1.x; bh0.u[3] = r1.y;
          bh1.u[0] = r2.x; bh1.u[1] = r2.y; bh1.u[2] = r3.x; bh1.u[3] = r3.y; }

        // ---- layer 3 + head (packed fma accumulation) ----
        h = __builtin_amdgcn_mfma_f32_32x32x16_bf16(a3[0].v, bh0.v, c3, 0, 0, 0);
        h = __builtin_amdgcn_mfma_f32_32x32x16_bf16(a3[1].v, bh1.v, h,  0, 0, 0);

        f32x2 pacc = {0.0f, 0.0f};
        #pragma unroll
        for (int r = 0; r < 16; r += 2)
            pacc += act2(h[r], h[r+1]) * w4p[r >> 1];   // v_pk_fma_f32
        float part = pacc[0] + pacc[1];
        part += __shfl_xor(part, 32, 64);       // sum the two k-halves
        const float score = part + b4s;

        const float q   = dtv * gk;
        float wgt = exp2neg(q * q);
        wgt = (dtv >= 0.0f) ? wgt : 0.0f;
        acc = fmaf(score, wgt, acc);
    }

    // reduce over the 32 dose-columns (halves are duplicates)
    #pragma unroll
    for (int off = 1; off < 32; off <<= 1)
        acc += __shfl_xor(acc, off, 64);
    if (lane == 0) out[t] = acc;
}

extern "C" void kernel_launch(void* const* d_in, const int* in_sizes, int n_in,
                              void* d_out, int out_size, void* d_ws, size_t ws_size,
                              hipStream_t stream) {
    const float* t_abs  = (const float*)d_in[0];
    const float* dose_t = (const float*)d_in[1];
    const float* amts   = (const float*)d_in[2];
    const float* ss     = (const float*)d_in[3];
    const float* ii     = (const float*)d_in[4];
    const float* span_p = (const float*)d_in[5];
    const float* logsig = (const float*)d_in[6];
    const float* W1 = (const float*)d_in[7];
    const float* b1 = (const float*)d_in[8];
    const float* W2 = (const float*)d_in[9];
    const float* b2 = (const float*)d_in[10];
    const float* W3 = (const float*)d_in[11];
    const float* b3 = (const float*)d_in[12];
    const float* W4 = (const float*)d_in[13];
    const float* b4 = (const float*)d_in[14];
    float* out = (float*)d_out;

    dose_encoder_kernel<<<dim3(T_N / 4), dim3(256), 0, stream>>>(
        t_abs, dose_t, amts, ss, ii, span_p, logsig,
        W1, b1, W2, b2, W3, b3, W4, b4, out);
}